// Round 11
// baseline (314.802 us; speedup 1.0000x reference)
//
#include <hip/hip_runtime.h>
#include <math.h>

typedef float f32x4 __attribute__((ext_vector_type(4)));
typedef short s16x8 __attribute__((ext_vector_type(8)));

#define DIM_ 768
#define HEADS_ 12
#define DH_ 64
#define HID_ 3072
#define SEQ_ 1024
#define BATCH_ 8
#define ROWS_ (BATCH_*SEQ_)   // 8192

static __device__ __forceinline__ ushort f2bf(float f) {
    union { float f; unsigned u; } v; v.f = f;
    unsigned r = (v.u + 0x7fffu + ((v.u >> 16) & 1u)) >> 16;
    return (ushort)r;
}

static __device__ __forceinline__ void glds16(const ushort* gp, ushort* lp) {
    __builtin_amdgcn_global_load_lds(
        (const __attribute__((address_space(1))) void*)gp,
        (__attribute__((address_space(3))) void*)lp, 16, 0, 0);
}

// ---------------- prep: cast x to bf16 ----------------
__global__ __launch_bounds__(256) void cast_bf16_kernel(
    const float* __restrict__ in, ushort* __restrict__ out, int n4)
{
    int i = blockIdx.x * 256 + threadIdx.x;
    if (i >= n4) return;
    float4 v = ((const float4*)in)[i];
    ushort4 o;
    o.x = f2bf(v.x); o.y = f2bf(v.y); o.z = f2bf(v.z); o.w = f2bf(v.w);
    ((ushort4*)out)[i] = o;
}

// ---------------- prep: transpose+cast W[K][N] -> WT[N][K] bf16 ----------------
__global__ __launch_bounds__(256) void transpose_cast_kernel(
    const float* __restrict__ W, ushort* __restrict__ WT, int K, int N)
{
    __shared__ float tile[32][33];
    int n0 = blockIdx.x * 32, k0 = blockIdx.y * 32;
    int tx = threadIdx.x, ty = threadIdx.y; // 32 x 8
#pragma unroll
    for (int i = 0; i < 4; i++)
        tile[ty + i * 8][tx] = W[(size_t)(k0 + ty + i * 8) * N + n0 + tx];
    __syncthreads();
#pragma unroll
    for (int i = 0; i < 4; i++)
        WT[(size_t)(n0 + ty + i * 8) * K + k0 + tx] = f2bf(tile[tx][ty + i * 8]);
}

// ---------------- GEMM: C = A @ BT^T + bias (R7-validated, occupancy 3) ----------------
#define EPI_F32 0
#define EPI_GELU 1
#define EPI_QKV 2

template<int EPI>
__global__ __launch_bounds__(256, 3) void gemm_bt(
    const ushort* __restrict__ A, const ushort* __restrict__ B,
    const float* __restrict__ bias,
    float* __restrict__ Cf, ushort* __restrict__ Cbf,
    ushort* __restrict__ Qb, ushort* __restrict__ Kb, ushort* __restrict__ Vt,
    int M, int N, int K, int nx, int nk, int Ksl)
{
    __shared__ ushort As[128 * 64];
    __shared__ ushort Bs[128 * 64];
    const int t = threadIdx.x;
    const int lane = t & 63;
    const int w = t >> 6;
    const int wr = w >> 1, wc = w & 1;
    const int nwg = gridDim.x;
    const int chunk = nwg >> 3;
    const int lin = (blockIdx.x & 7) * chunk + (blockIdx.x >> 3);
    const int tile = lin / nk;
    const int ks = lin - tile * nk;
    const int m0 = (tile / nx) * 128, n0 = (tile % nx) * 128;
    const int lr = lane & 15, g = lane >> 4;

    const ushort* Ak = A + (size_t)ks * Ksl;
    const ushort* Bk = B + (size_t)ks * Ksl;
    const int sr = lane >> 3;
    const int scz = (((lane & 7) ^ sr)) * 8;

    f32x4 acc[4][4] = {};

    for (int k0 = 0; k0 < Ksl; k0 += 64) {
#pragma unroll
        for (int j = 0; j < 4; j++) {
            int r = w * 32 + j * 8;
            glds16(Ak + (size_t)(m0 + r + sr) * K + k0 + scz, &As[r * 64]);
            glds16(Bk + (size_t)(n0 + r + sr) * K + k0 + scz, &Bs[r * 64]);
        }
        __syncthreads();
#pragma unroll
        for (int kk = 0; kk < 2; kk++) {
            s16x8 af[4], bfr[4];
#pragma unroll
            for (int m = 0; m < 4; m++) {
                int row = wr * 64 + m * 16 + lr;
                int slot = (kk * 4 + g) ^ (row & 7);
                af[m] = *(const s16x8*)&As[row * 64 + slot * 8];
            }
#pragma unroll
            for (int n = 0; n < 4; n++) {
                int row = wc * 64 + n * 16 + lr;
                int slot = (kk * 4 + g) ^ (row & 7);
                bfr[n] = *(const s16x8*)&Bs[row * 64 + slot * 8];
            }
#pragma unroll
            for (int m = 0; m < 4; m++)
#pragma unroll
                for (int n = 0; n < 4; n++)
                    acc[m][n] = __builtin_amdgcn_mfma_f32_16x16x32_bf16(af[m], bfr[n], acc[m][n], 0, 0, 0);
        }
        __syncthreads();
    }

    float* Cfo = Cf ? Cf + (size_t)ks * M * N : nullptr;
#pragma unroll
    for (int m = 0; m < 4; m++) {
        int row = m0 + wr * 64 + m * 16 + g * 4;
#pragma unroll
        for (int n = 0; n < 4; n++) {
            int col = n0 + wc * 64 + n * 16 + lr;
            float bv = (ks == 0) ? bias[col] : 0.f;
#pragma unroll
            for (int r = 0; r < 4; r++) {
                float v = acc[m][n][r] + bv;
                int rg = row + r;
                if (EPI == EPI_F32) {
                    Cfo[(size_t)rg * N + col] = v;
                } else if (EPI == EPI_GELU) {
                    float gl = 0.5f * v * (1.0f + erff(v * 0.70710678118654752f));
                    Cbf[(size_t)rg * N + col] = f2bf(gl);
                } else { // QKV scatter: col = h*192 + dh*3 + which
                    int b = rg >> 10, nrow = rg & 1023;
                    int h = col / 192, rem = col % 192;
                    int dh = rem / 3, wh = rem % 3;
                    int hb = b * HEADS_ + h;
                    ushort bw = f2bf(v);
                    if (wh == 0)      Qb[((size_t)hb * SEQ_ + nrow) * DH_ + dh] = bw;
                    else if (wh == 1) Kb[((size_t)hb * SEQ_ + nrow) * DH_ + dh] = bw;
                    else              Vt[(size_t)hb * DH_ * SEQ_ + (size_t)dh * SEQ_ + nrow] = bw;
                }
            }
        }
    }
}

// ---- pack P (f32, post-exp) into PV A-frags via cvt_pk + permlane swaps ----
static __device__ __forceinline__ void pack_pv(
    const f32x4 (&S)[4], s16x8& pf0v, s16x8& pf1v)
{
    unsigned c[4][2];
#pragma unroll
    for (int n = 0; n < 4; n++) {
        asm("v_cvt_pk_bf16_f32 %0, %1, %2" : "=v"(c[n][0]) : "v"(S[n][0]), "v"(S[n][1]));
        asm("v_cvt_pk_bf16_f32 %0, %1, %2" : "=v"(c[n][1]) : "v"(S[n][2]), "v"(S[n][3]));
    }
    union { unsigned u[4]; s16x8 v; } pf0, pf1;
#pragma unroll
    for (int m = 0; m < 2; m++) {
        unsigned a = c[0][m], bb = c[1][m];
        asm("v_permlane32_swap_b32 %0, %1" : "+v"(a), "+v"(bb));
        asm("v_permlane16_swap_b32 %0, %1" : "+v"(a), "+v"(bb));
        pf0.u[m] = a; pf0.u[2 + m] = bb;
        unsigned a2 = c[2][m], b2 = c[3][m];
        asm("v_permlane32_swap_b32 %0, %1" : "+v"(a2), "+v"(b2));
        asm("v_permlane16_swap_b32 %0, %1" : "+v"(a2), "+v"(b2));
        pf1.u[m] = a2; pf1.u[2 + m] = b2;
    }
    pf0v = pf0.v; pf1v = pf1.v;
}

// ---------------- flash attention v8: REAL K+V register double-buffer ----------------
// launch_bounds(256,2): VGPR budget 256 so kc/kn/vc/vn (+128 VGPR) stay live;
// sched_barrier(0) pins load-issue points so regalloc can't sink the prefetch.
// Loads stay async in flight across the other tile's compute (s_waitcnt lands
// at first use). Occupancy 3->2 blocks/CU: same ILP-for-TLP trade R4 won.
struct AttnState {
    s16x8 aqA0, aqA1, aqB0, aqB1;
    float lA, lB;
    f32x4 OA[4], OB[4];
};

static __device__ __forceinline__ void attn_tile(
    AttnState& st, const s16x8 (&kcur)[8], const s16x8 (&vcur)[8])
{
    const float CMAX = 20.f;
    f32x4 SA[4] = {}, SB[4] = {};
#pragma unroll
    for (int n = 0; n < 4; n++) {
        SA[n] = __builtin_amdgcn_mfma_f32_16x16x32_bf16(kcur[2 * n], st.aqA0, SA[n], 0, 0, 0);
        SA[n] = __builtin_amdgcn_mfma_f32_16x16x32_bf16(kcur[2 * n + 1], st.aqA1, SA[n], 0, 0, 0);
    }
#pragma unroll
    for (int n = 0; n < 4; n++) {
        SB[n] = __builtin_amdgcn_mfma_f32_16x16x32_bf16(kcur[2 * n], st.aqB0, SB[n], 0, 0, 0);
        SB[n] = __builtin_amdgcn_mfma_f32_16x16x32_bf16(kcur[2 * n + 1], st.aqB1, SB[n], 0, 0, 0);
    }
#pragma unroll
    for (int n = 0; n < 4; n++)
#pragma unroll
        for (int r = 0; r < 4; r++) {
            SA[n][r] = __expf(SA[n][r] - CMAX);
            SB[n][r] = __expf(SB[n][r] - CMAX);
        }
    f32x4 sa = SA[0] + SA[1], sb = SB[0] + SB[1];
    sa += SA[2] + SA[3];
    sb += SB[2] + SB[3];
    st.lA += (sa[0] + sa[1]) + (sa[2] + sa[3]);
    st.lB += (sb[0] + sb[1]) + (sb[2] + sb[3]);

    s16x8 pfA0, pfA1, pfB0, pfB1;
    pack_pv(SA, pfA0, pfA1);
    pack_pv(SB, pfB0, pfB1);

#pragma unroll
    for (int n = 0; n < 4; n++) {
        st.OA[n] = __builtin_amdgcn_mfma_f32_16x16x32_bf16(pfA0, vcur[2 * n], st.OA[n], 0, 0, 0);
        st.OA[n] = __builtin_amdgcn_mfma_f32_16x16x32_bf16(pfA1, vcur[2 * n + 1], st.OA[n], 0, 0, 0);
    }
#pragma unroll
    for (int n = 0; n < 4; n++) {
        st.OB[n] = __builtin_amdgcn_mfma_f32_16x16x32_bf16(pfB0, vcur[2 * n], st.OB[n], 0, 0, 0);
        st.OB[n] = __builtin_amdgcn_mfma_f32_16x16x32_bf16(pfB1, vcur[2 * n + 1], st.OB[n], 0, 0, 0);
    }
}

static __device__ __forceinline__ void load_ktile(
    const ushort* kh, int kbase, int lr, int g, s16x8 (&kd)[8])
{
#pragma unroll
    for (int n = 0; n < 4; n++) {
        const ushort* kp = kh + (size_t)(kbase + n * 16 + lr) * DH_ + g * 8;
        kd[2 * n]     = *(const s16x8*)kp;
        kd[2 * n + 1] = *(const s16x8*)(kp + 32);
    }
}

static __device__ __forceinline__ void load_vtile(
    const ushort* vh, int kbase, int lr, int g, s16x8 (&vd)[8])
{
#pragma unroll
    for (int n = 0; n < 4; n++) {
        const ushort* vp = vh + (size_t)(n * 16 + lr) * SEQ_ + kbase + g * 8;
        vd[2 * n]     = *(const s16x8*)vp;
        vd[2 * n + 1] = *(const s16x8*)(vp + 32);
    }
}

__global__ __launch_bounds__(256, 2) void attn_kernel(
    const ushort* __restrict__ Q, const ushort* __restrict__ Kb,
    const ushort* __restrict__ Vt, ushort* __restrict__ AO)
{
    const int t = threadIdx.x, lane = t & 63, w = t >> 6;
    const int lr = lane & 15, g = lane >> 4;
    const int wg = blockIdx.x;                 // 0..767
    const int lin = (wg & 7) * 96 + (wg >> 3); // XCD-contiguous work id
    const int bh = lin >> 3;                   // 12 heads per XCD
    const int qt = lin & 7;
    const int b = bh / HEADS_, h = bh % HEADS_;
    const ushort* qh = Q + (size_t)bh * SEQ_ * DH_;
    const ushort* kh = Kb + (size_t)bh * SEQ_ * DH_;
    const ushort* vh = Vt + (size_t)bh * DH_ * SEQ_;

    AttnState st;
    const int qbase = qt * 128 + w * 32;
    st.aqA0 = *(const s16x8*)(qh + (size_t)(qbase + lr) * DH_ + g * 8);
    st.aqA1 = *(const s16x8*)(qh + (size_t)(qbase + lr) * DH_ + 32 + g * 8);
    st.aqB0 = *(const s16x8*)(qh + (size_t)(qbase + 16 + lr) * DH_ + g * 8);
    st.aqB1 = *(const s16x8*)(qh + (size_t)(qbase + 16 + lr) * DH_ + 32 + g * 8);
    st.lA = 0.f; st.lB = 0.f;
#pragma unroll
    for (int n = 0; n < 4; n++) { st.OA[n] = f32x4{}; st.OB[n] = f32x4{}; }

    s16x8 kc[8], kn[8], vc[8], vn[8];
    load_ktile(kh, 0, lr, g, kc);
    load_vtile(vh, 0, lr, g, vc);

#pragma unroll 1
    for (int tkv = 0; tkv < 16; tkv += 2) {
        // issue odd-tile prefetch, pin issue point, then compute even tile
        load_ktile(kh, (tkv + 1) * 64, lr, g, kn);
        load_vtile(vh, (tkv + 1) * 64, lr, g, vn);
        __builtin_amdgcn_sched_barrier(0);
        attn_tile(st, kc, vc);
        // issue next-even prefetch, pin, compute odd tile
        if (tkv + 2 < 16) {
            load_ktile(kh, (tkv + 2) * 64, lr, g, kc);
            load_vtile(vh, (tkv + 2) * 64, lr, g, vc);
        }
        __builtin_amdgcn_sched_barrier(0);
        attn_tile(st, kn, vn);
    }

    float lA = st.lA, lB = st.lB;
    lA += __shfl_xor(lA, 16); lA += __shfl_xor(lA, 32);
    lB += __shfl_xor(lB, 16); lB += __shfl_xor(lB, 32);

    const float fin = 0.03608439182435161f; // 1/sqrt(768), applied post-softmax
#pragma unroll
    for (int r = 0; r < 4; r++) {
        float linvA = fin / __shfl(lA, 4 * g + r);
        float linvB = fin / __shfl(lB, 4 * g + r);
        int rowA = b * SEQ_ + qbase + 4 * g + r;
        int rowB = rowA + 16;
        ushort* aoA = AO + (size_t)rowA * DIM_ + h * DH_ + lr;
        ushort* aoB = AO + (size_t)rowB * DIM_ + h * DH_ + lr;
#pragma unroll
        for (int n = 0; n < 4; n++) {
            aoA[n * 16] = f2bf(st.OA[n][r] * linvA);
            aoB[n * 16] = f2bf(st.OB[n][r] * linvB);
        }
    }
}

// ---------------- fused residual + LayerNorm (wave per row, float4) ----------------
__global__ __launch_bounds__(256) void ln_residual_kernel(
    const float* __restrict__ xin, const float* __restrict__ y0,
    const float* __restrict__ y1,
    const float* __restrict__ g, const float* __restrict__ be,
    float* __restrict__ outf, ushort* __restrict__ outbf, int rows)
{
    int w = threadIdx.x >> 6, lane = threadIdx.x & 63;
    int row = blockIdx.x * 4 + w;
    if (row >= rows) return;
    const float4* y0r = (const float4*)(y0 + (size_t)row * DIM_);
    const float4* y1r = y1 ? (const float4*)(y1 + (size_t)row * DIM_) : nullptr;
    float4 v[3];
    float s = 0.f, s2 = 0.f;
#pragma unroll
    for (int i = 0; i < 3; i++) {
        float4 a = y0r[i * 64 + lane];
        if (y1r) {
            float4 bb = y1r[i * 64 + lane];
            a.x += bb.x; a.y += bb.y; a.z += bb.z; a.w += bb.w;
        }
        v[i] = a;
        s += (a.x + a.y) + (a.z + a.w);
        s2 += (a.x * a.x + a.y * a.y) + (a.z * a.z + a.w * a.w);
    }
#pragma unroll
    for (int o = 1; o < 64; o <<= 1) { s += __shfl_xor(s, o); s2 += __shfl_xor(s2, o); }
    float mu = s * (1.f / 768.f);
    float var = s2 * (1.f / 768.f) - mu * mu;
    float rs = rsqrtf(var + 1e-5f);
    const float4* xr = (const float4*)(xin + (size_t)row * DIM_);
    const float4* g4 = (const float4*)g;
    const float4* b4 = (const float4*)be;
    float4* of = (float4*)(outf + (size_t)row * DIM_);
#pragma unroll
    for (int i = 0; i < 3; i++) {
        int c = i * 64 + lane;
        float4 gg = g4[c], bb = b4[c], xx = xr[c];
        float4 o;
        o.x = xx.x + (v[i].x - mu) * rs * gg.x + bb.x;
        o.y = xx.y + (v[i].y - mu) * rs * gg.y + bb.y;
        o.z = xx.z + (v[i].z - mu) * rs * gg.z + bb.z;
        o.w = xx.w + (v[i].w - mu) * rs * gg.w + bb.w;
        of[c] = o;
        if (outbf) {
            ushort4 ob;
            ob.x = f2bf(o.x); ob.y = f2bf(o.y); ob.z = f2bf(o.z); ob.w = f2bf(o.w);
            ((ushort4*)(outbf + (size_t)row * DIM_))[c] = ob;
        }
    }
}

// ---------------- launch ----------------
extern "C" void kernel_launch(void* const* d_in, const int* in_sizes, int n_in,
                              void* d_out, int out_size, void* d_ws, size_t ws_size,
                              hipStream_t stream)
{
    const float* x    = (const float*)d_in[0];
    const float* Wqkv = (const float*)d_in[1];
    const float* bqkv = (const float*)d_in[2];
    const float* Wproj= (const float*)d_in[3];
    const float* bproj= (const float*)d_in[4];
    const float* W1   = (const float*)d_in[5];
    const float* b1   = (const float*)d_in[6];
    const float* W2   = (const float*)d_in[7];
    const float* b2   = (const float*)d_in[8];
    const float* g1   = (const float*)d_in[9];
    const float* be1  = (const float*)d_in[10];
    const float* g2   = (const float*)d_in[11];
    const float* be2  = (const float*)d_in[12];
    float* out = (float*)d_out;

    char* ws = (char*)d_ws;
    size_t off = 0;
    auto alloc = [&](size_t bytes) -> void* {
        void* p = ws + off;
        off += (bytes + 255) & ~(size_t)255;
        return p;
    };
    // weights first (live all along)
    ushort* wqkvT  = (ushort*)alloc((size_t)2304 * 768 * 2);
    ushort* wprojT = (ushort*)alloc((size_t)768 * 768 * 2);
    ushort* w1T    = (ushort*)alloc((size_t)3072 * 768 * 2);
    ushort* w2T    = (ushort*)alloc((size_t)768 * 3072 * 2);
    // BLOCK_A: xbf/qb/kb/vT (dead after attn) — aliased by hbf afterwards.
    ushort* xbf    = (ushort*)alloc((size_t)ROWS_ * DIM_ * 2);
    ushort* qb     = (ushort*)alloc((size_t)ROWS_ * DIM_ * 2);
    ushort* kb     = (ushort*)alloc((size_t)ROWS_ * DIM_ * 2);
    ushort* vT     = (ushort*)alloc((size_t)ROWS_ * DIM_ * 2);
    ushort* hbf    = xbf;  // alias: 4*ROWS*DIM*2 == ROWS*HID*2
    ushort* aobf   = (ushort*)alloc((size_t)ROWS_ * DIM_ * 2);
    float*  projp  = (float*) alloc((size_t)2 * ROWS_ * DIM_ * 4); // split-K partials
    float*  x1f    = (float*) alloc((size_t)ROWS_ * DIM_ * 4);
    ushort* x1bf   = (ushort*)alloc((size_t)ROWS_ * DIM_ * 2);
    float*  projp1 = projp + (size_t)ROWS_ * DIM_;

    // prep
    cast_bf16_kernel<<<(ROWS_ * DIM_ / 4 + 255) / 256, 256, 0, stream>>>(x, xbf, ROWS_ * DIM_ / 4);
    transpose_cast_kernel<<<dim3(2304 / 32, 768 / 32), dim3(32, 8), 0, stream>>>(Wqkv, wqkvT, 768, 2304);
    transpose_cast_kernel<<<dim3(768 / 32, 768 / 32), dim3(32, 8), 0, stream>>>(Wproj, wprojT, 768, 768);
    transpose_cast_kernel<<<dim3(3072 / 32, 768 / 32), dim3(32, 8), 0, stream>>>(W1, w1T, 768, 3072);
    transpose_cast_kernel<<<dim3(768 / 32, 3072 / 32), dim3(32, 8), 0, stream>>>(W2, w2T, 3072, 768);

    // qkv = x @ Wqkv + bqkv -> scatter into q/k/vT  (1152 blocks, nx=18)
    gemm_bt<EPI_QKV><<<1152, 256, 0, stream>>>(
        xbf, wqkvT, bqkv, nullptr, nullptr, qb, kb, vT, ROWS_, 2304, 768, 18, 1, 768);

    // attention -> aobf (768 blocks, XCD-local heads)
    attn_kernel<<<768, 256, 0, stream>>>(qb, kb, vT, aobf);

    // proj: split-K x2 (768 blocks, nx=6, Ksl=384) -> projp0, projp1
    gemm_bt<EPI_F32><<<768, 256, 0, stream>>>(
        aobf, wprojT, bproj, projp, nullptr, nullptr, nullptr, nullptr, ROWS_, 768, 768, 6, 2, 384);

    // x1 = x + LN(projp0 + projp1)
    ln_residual_kernel<<<ROWS_ / 4, 256, 0, stream>>>(x, projp, projp1, g1, be1, x1f, x1bf, ROWS_);

    // h = gelu(x1 @ W1 + b1)  (1536 blocks, nx=24) — hbf aliases dead BLOCK_A
    gemm_bt<EPI_GELU><<<1536, 256, 0, stream>>>(
        x1bf, w1T, b1, nullptr, hbf, nullptr, nullptr, nullptr, ROWS_, 3072, 768, 24, 1, 768);

    // mlp = h @ W2 + b2: split-K x2 (768 blocks, nx=6, Ksl=1536) -> projp0, projp1
    gemm_bt<EPI_F32><<<768, 256, 0, stream>>>(
        hbf, w2T, b2, projp, nullptr, nullptr, nullptr, nullptr, ROWS_, 768, 3072, 6, 2, 1536);

    // out = x1 + LN(mlp0 + mlp1)
    ln_residual_kernel<<<ROWS_ / 4, 256, 0, stream>>>(x1f, projp, projp1, g2, be2, out, nullptr, ROWS_);
}

// Round 13
// 268.630 us; speedup vs baseline: 1.1719x; 1.1719x over previous
//
#include <hip/hip_runtime.h>
#include <math.h>

typedef float f32x4 __attribute__((ext_vector_type(4)));
typedef short s16x8 __attribute__((ext_vector_type(8)));

#define DIM_ 768
#define HEADS_ 12
#define DH_ 64
#define HID_ 3072
#define SEQ_ 1024
#define BATCH_ 8
#define ROWS_ (BATCH_*SEQ_)   // 8192

static __device__ __forceinline__ ushort f2bf(float f) {
    union { float f; unsigned u; } v; v.f = f;
    unsigned r = (v.u + 0x7fffu + ((v.u >> 16) & 1u)) >> 16;
    return (ushort)r;
}

static __device__ __forceinline__ void glds16(const ushort* gp, ushort* lp) {
    __builtin_amdgcn_global_load_lds(
        (const __attribute__((address_space(1))) void*)gp,
        (__attribute__((address_space(3))) void*)lp, 16, 0, 0);
}

// ---------------- prep: cast x to bf16 ----------------
__global__ __launch_bounds__(256) void cast_bf16_kernel(
    const float* __restrict__ in, ushort* __restrict__ out, int n4)
{
    int i = blockIdx.x * 256 + threadIdx.x;
    if (i >= n4) return;
    float4 v = ((const float4*)in)[i];
    ushort4 o;
    o.x = f2bf(v.x); o.y = f2bf(v.y); o.z = f2bf(v.z); o.w = f2bf(v.w);
    ((ushort4*)out)[i] = o;
}

// ---------------- prep: transpose+cast W[K][N] -> WT[N][K] bf16 ----------------
__global__ __launch_bounds__(256) void transpose_cast_kernel(
    const float* __restrict__ W, ushort* __restrict__ WT, int K, int N)
{
    __shared__ float tile[32][33];
    int n0 = blockIdx.x * 32, k0 = blockIdx.y * 32;
    int tx = threadIdx.x, ty = threadIdx.y; // 32 x 8
#pragma unroll
    for (int i = 0; i < 4; i++)
        tile[ty + i * 8][tx] = W[(size_t)(k0 + ty + i * 8) * N + n0 + tx];
    __syncthreads();
#pragma unroll
    for (int i = 0; i < 4; i++)
        WT[(size_t)(n0 + ty + i * 8) * K + k0 + tx] = f2bf(tile[tx][ty + i * 8]);
}

// ---------------- GEMM: C = A @ BT^T + bias (R7-validated, occupancy 3) ----------------
#define EPI_F32 0
#define EPI_GELU 1
#define EPI_QKV 2

template<int EPI>
__global__ __launch_bounds__(256, 3) void gemm_bt(
    const ushort* __restrict__ A, const ushort* __restrict__ B,
    const float* __restrict__ bias,
    float* __restrict__ Cf, ushort* __restrict__ Cbf,
    ushort* __restrict__ Qb, ushort* __restrict__ Kb, ushort* __restrict__ Vt,
    int M, int N, int K, int nx, int nk, int Ksl)
{
    __shared__ ushort As[128 * 64];
    __shared__ ushort Bs[128 * 64];
    const int t = threadIdx.x;
    const int lane = t & 63;
    const int w = t >> 6;
    const int wr = w >> 1, wc = w & 1;
    const int nwg = gridDim.x;
    const int chunk = nwg >> 3;
    const int lin = (blockIdx.x & 7) * chunk + (blockIdx.x >> 3);
    const int tile = lin / nk;
    const int ks = lin - tile * nk;
    const int m0 = (tile / nx) * 128, n0 = (tile % nx) * 128;
    const int lr = lane & 15, g = lane >> 4;

    const ushort* Ak = A + (size_t)ks * Ksl;
    const ushort* Bk = B + (size_t)ks * Ksl;
    const int sr = lane >> 3;
    const int scz = (((lane & 7) ^ sr)) * 8;

    f32x4 acc[4][4] = {};

    for (int k0 = 0; k0 < Ksl; k0 += 64) {
#pragma unroll
        for (int j = 0; j < 4; j++) {
            int r = w * 32 + j * 8;
            glds16(Ak + (size_t)(m0 + r + sr) * K + k0 + scz, &As[r * 64]);
            glds16(Bk + (size_t)(n0 + r + sr) * K + k0 + scz, &Bs[r * 64]);
        }
        __syncthreads();
#pragma unroll
        for (int kk = 0; kk < 2; kk++) {
            s16x8 af[4], bfr[4];
#pragma unroll
            for (int m = 0; m < 4; m++) {
                int row = wr * 64 + m * 16 + lr;
                int slot = (kk * 4 + g) ^ (row & 7);
                af[m] = *(const s16x8*)&As[row * 64 + slot * 8];
            }
#pragma unroll
            for (int n = 0; n < 4; n++) {
                int row = wc * 64 + n * 16 + lr;
                int slot = (kk * 4 + g) ^ (row & 7);
                bfr[n] = *(const s16x8*)&Bs[row * 64 + slot * 8];
            }
#pragma unroll
            for (int m = 0; m < 4; m++)
#pragma unroll
                for (int n = 0; n < 4; n++)
                    acc[m][n] = __builtin_amdgcn_mfma_f32_16x16x32_bf16(af[m], bfr[n], acc[m][n], 0, 0, 0);
        }
        __syncthreads();
    }

    float* Cfo = Cf ? Cf + (size_t)ks * M * N : nullptr;
#pragma unroll
    for (int m = 0; m < 4; m++) {
        int row = m0 + wr * 64 + m * 16 + g * 4;
#pragma unroll
        for (int n = 0; n < 4; n++) {
            int col = n0 + wc * 64 + n * 16 + lr;
            float bv = (ks == 0) ? bias[col] : 0.f;
#pragma unroll
            for (int r = 0; r < 4; r++) {
                float v = acc[m][n][r] + bv;
                int rg = row + r;
                if (EPI == EPI_F32) {
                    Cfo[(size_t)rg * N + col] = v;
                } else if (EPI == EPI_GELU) {
                    float gl = 0.5f * v * (1.0f + erff(v * 0.70710678118654752f));
                    Cbf[(size_t)rg * N + col] = f2bf(gl);
                } else { // QKV scatter: col = h*192 + dh*3 + which
                    int b = rg >> 10, nrow = rg & 1023;
                    int h = col / 192, rem = col % 192;
                    int dh = rem / 3, wh = rem % 3;
                    int hb = b * HEADS_ + h;
                    ushort bw = f2bf(v);
                    if (wh == 0)      Qb[((size_t)hb * SEQ_ + nrow) * DH_ + dh] = bw;
                    else if (wh == 1) Kb[((size_t)hb * SEQ_ + nrow) * DH_ + dh] = bw;
                    else              Vt[(size_t)hb * DH_ * SEQ_ + (size_t)dh * SEQ_ + nrow] = bw;
                }
            }
        }
    }
}

// ---- pack P (f32, post-exp) into PV A-frags via cvt_pk + permlane swaps ----
static __device__ __forceinline__ void pack_pv(
    const f32x4 (&S)[4], s16x8& pf0v, s16x8& pf1v)
{
    unsigned c[4][2];
#pragma unroll
    for (int n = 0; n < 4; n++) {
        asm("v_cvt_pk_bf16_f32 %0, %1, %2" : "=v"(c[n][0]) : "v"(S[n][0]), "v"(S[n][1]));
        asm("v_cvt_pk_bf16_f32 %0, %1, %2" : "=v"(c[n][1]) : "v"(S[n][2]), "v"(S[n][3]));
    }
    union { unsigned u[4]; s16x8 v; } pf0, pf1;
#pragma unroll
    for (int m = 0; m < 2; m++) {
        unsigned a = c[0][m], bb = c[1][m];
        asm("v_permlane32_swap_b32 %0, %1" : "+v"(a), "+v"(bb));
        asm("v_permlane16_swap_b32 %0, %1" : "+v"(a), "+v"(bb));
        pf0.u[m] = a; pf0.u[2 + m] = bb;
        unsigned a2 = c[2][m], b2 = c[3][m];
        asm("v_permlane32_swap_b32 %0, %1" : "+v"(a2), "+v"(b2));
        asm("v_permlane16_swap_b32 %0, %1" : "+v"(a2), "+v"(b2));
        pf1.u[m] = a2; pf1.u[2 + m] = b2;
    }
    pf0v = pf0.v; pf1v = pf1.v;
}

// ---------------- flash attention v9: LDS-staged K/V, ping-pong, async glds ----
// K/V staged once per BLOCK (not per wave) via global_load_lds (no VGPR dest ->
// regalloc can't sink it). One __syncthreads per tile drains vmcnt once,
// overlapped with the previous tile's compute. XOR slot-swizzle (rule 21:
// pre-swizzled SOURCE + same-XOR read) kills the 16-way row-conflict.
// Softmax math identical to validated R8 kernel (fixed shift C=20).
struct AttnState {
    s16x8 aqA0, aqA1, aqB0, aqB1;
    float lA, lB;
    f32x4 OA[4], OB[4];
};

static __device__ __forceinline__ void attn_tile_lds(
    AttnState& st, const ushort* Ksb, const ushort* Vsb, int lr, int g)
{
    const float CMAX = 20.f;
    const int x = lr & 7;
    s16x8 kf[8], vf[8];
#pragma unroll
    for (int n = 0; n < 4; n++) {
        int row = n * 16 + lr;
        kf[2 * n]     = *(const s16x8*)&Ksb[row * 64 + (g ^ x) * 8];
        kf[2 * n + 1] = *(const s16x8*)&Ksb[row * 64 + ((4 + g) ^ x) * 8];
        vf[2 * n]     = *(const s16x8*)&Vsb[row * 64 + (g ^ x) * 8];
        vf[2 * n + 1] = *(const s16x8*)&Vsb[row * 64 + ((4 + g) ^ x) * 8];
    }
    f32x4 SA[4] = {}, SB[4] = {};
#pragma unroll
    for (int n = 0; n < 4; n++) {
        SA[n] = __builtin_amdgcn_mfma_f32_16x16x32_bf16(kf[2 * n], st.aqA0, SA[n], 0, 0, 0);
        SA[n] = __builtin_amdgcn_mfma_f32_16x16x32_bf16(kf[2 * n + 1], st.aqA1, SA[n], 0, 0, 0);
    }
#pragma unroll
    for (int n = 0; n < 4; n++) {
        SB[n] = __builtin_amdgcn_mfma_f32_16x16x32_bf16(kf[2 * n], st.aqB0, SB[n], 0, 0, 0);
        SB[n] = __builtin_amdgcn_mfma_f32_16x16x32_bf16(kf[2 * n + 1], st.aqB1, SB[n], 0, 0, 0);
    }
#pragma unroll
    for (int n = 0; n < 4; n++)
#pragma unroll
        for (int r = 0; r < 4; r++) {
            SA[n][r] = __expf(SA[n][r] - CMAX);
            SB[n][r] = __expf(SB[n][r] - CMAX);
        }
    f32x4 sa = SA[0] + SA[1], sb = SB[0] + SB[1];
    sa += SA[2] + SA[3];
    sb += SB[2] + SB[3];
    st.lA += (sa[0] + sa[1]) + (sa[2] + sa[3]);
    st.lB += (sb[0] + sb[1]) + (sb[2] + sb[3]);

    s16x8 pfA0, pfA1, pfB0, pfB1;
    pack_pv(SA, pfA0, pfA1);
    pack_pv(SB, pfB0, pfB1);

#pragma unroll
    for (int n = 0; n < 4; n++) {
        st.OA[n] = __builtin_amdgcn_mfma_f32_16x16x32_bf16(pfA0, vf[2 * n], st.OA[n], 0, 0, 0);
        st.OA[n] = __builtin_amdgcn_mfma_f32_16x16x32_bf16(pfA1, vf[2 * n + 1], st.OA[n], 0, 0, 0);
    }
#pragma unroll
    for (int n = 0; n < 4; n++) {
        st.OB[n] = __builtin_amdgcn_mfma_f32_16x16x32_bf16(pfB0, vf[2 * n], st.OB[n], 0, 0, 0);
        st.OB[n] = __builtin_amdgcn_mfma_f32_16x16x32_bf16(pfB1, vf[2 * n + 1], st.OB[n], 0, 0, 0);
    }
}

__global__ __launch_bounds__(256) void attn_kernel(
    const ushort* __restrict__ Q, const ushort* __restrict__ Kb,
    const ushort* __restrict__ Vt, ushort* __restrict__ AO)
{
    __shared__ ushort Ks[2][64 * 64];
    __shared__ ushort Vs[2][64 * 64];
    const int tid = threadIdx.x, lane = tid & 63, w = tid >> 6;
    const int lr = lane & 15, g = lane >> 4;
    const int wg = blockIdx.x;                 // 0..767
    const int lin = (wg & 7) * 96 + (wg >> 3); // XCD-contiguous work id
    const int bh = lin >> 3;                   // 12 heads per XCD
    const int qt = lin & 7;
    const int b = bh / HEADS_, h = bh % HEADS_;
    const ushort* qh = Q + (size_t)bh * SEQ_ * DH_;
    const ushort* kh = Kb + (size_t)bh * SEQ_ * DH_;
    const ushort* vh = Vt + (size_t)bh * DH_ * SEQ_;

    // staging geometry: thread tid stages 16B slot (tid&7) of row (tid>>3)
    // (and row+32 in the second call); SOURCE slot pre-XOR'd by row&7 so the
    // XOR'd read recovers linear data (both-sides involution, rule 21).
    const int srow = tid >> 3;            // 0..31
    const int ss = (tid & 7) ^ (srow & 7); // source slot

    AttnState st;
    const int qbase = qt * 128 + w * 32;
    st.aqA0 = *(const s16x8*)(qh + (size_t)(qbase + lr) * DH_ + g * 8);
    st.aqA1 = *(const s16x8*)(qh + (size_t)(qbase + lr) * DH_ + 32 + g * 8);
    st.aqB0 = *(const s16x8*)(qh + (size_t)(qbase + 16 + lr) * DH_ + g * 8);
    st.aqB1 = *(const s16x8*)(qh + (size_t)(qbase + 16 + lr) * DH_ + 32 + g * 8);
    st.lA = 0.f; st.lB = 0.f;
#pragma unroll
    for (int n = 0; n < 4; n++) { st.OA[n] = f32x4{}; st.OB[n] = f32x4{}; }

    // stage(buf, tile): K rows contiguous (stride 64 elem); V rows stride SEQ_.
    auto stageK = [&](ushort* buf, int kbase) {
        glds16(kh + (size_t)(kbase + srow) * DH_ + ss * 8, &buf[tid * 8]);
        glds16(kh + (size_t)(kbase + 32 + srow) * DH_ + ss * 8, &buf[tid * 8 + 2048]);
    };
    auto stageV = [&](ushort* buf, int kbase) {
        glds16(vh + (size_t)srow * SEQ_ + kbase + ss * 8, &buf[tid * 8]);
        glds16(vh + (size_t)(32 + srow) * SEQ_ + kbase + ss * 8, &buf[tid * 8 + 2048]);
    };

    stageK(Ks[0], 0);
    stageV(Vs[0], 0);
    __syncthreads();   // drains vmcnt(0): tile 0 staged

#pragma unroll 1
    for (int tkv = 0; tkv < 16; tkv += 2) {
        // prefetch odd tile into buf1 (async, no VGPR), compute even from buf0
        if (tkv + 1 < 16) { stageK(Ks[1], (tkv + 1) * 64); stageV(Vs[1], (tkv + 1) * 64); }
        attn_tile_lds(st, Ks[0], Vs[0], lr, g);
        __syncthreads();  // odd tile staged; all reads of buf0 done
        // prefetch next even into buf0, compute odd from buf1
        if (tkv + 2 < 16) { stageK(Ks[0], (tkv + 2) * 64); stageV(Vs[0], (tkv + 2) * 64); }
        attn_tile_lds(st, Ks[1], Vs[1], lr, g);
        __syncthreads();  // next even staged; all reads of buf1 done
    }

    float lA = st.lA, lB = st.lB;
    lA += __shfl_xor(lA, 16); lA += __shfl_xor(lA, 32);
    lB += __shfl_xor(lB, 16); lB += __shfl_xor(lB, 32);

    const float fin = 0.03608439182435161f; // 1/sqrt(768), applied post-softmax
#pragma unroll
    for (int r = 0; r < 4; r++) {
        float linvA = fin / __shfl(lA, 4 * g + r);
        float linvB = fin / __shfl(lB, 4 * g + r);
        int rowA = b * SEQ_ + qbase + 4 * g + r;
        int rowB = rowA + 16;
        ushort* aoA = AO + (size_t)rowA * DIM_ + h * DH_ + lr;
        ushort* aoB = AO + (size_t)rowB * DIM_ + h * DH_ + lr;
#pragma unroll
        for (int n = 0; n < 4; n++) {
            aoA[n * 16] = f2bf(st.OA[n][r] * linvA);
            aoB[n * 16] = f2bf(st.OB[n][r] * linvB);
        }
    }
}

// ---------------- fused residual + LayerNorm (wave per row, float4) ----------------
__global__ __launch_bounds__(256) void ln_residual_kernel(
    const float* __restrict__ xin, const float* __restrict__ y0,
    const float* __restrict__ y1,
    const float* __restrict__ g, const float* __restrict__ be,
    float* __restrict__ outf, ushort* __restrict__ outbf, int rows)
{
    int w = threadIdx.x >> 6, lane = threadIdx.x & 63;
    int row = blockIdx.x * 4 + w;
    if (row >= rows) return;
    const float4* y0r = (const float4*)(y0 + (size_t)row * DIM_);
    const float4* y1r = y1 ? (const float4*)(y1 + (size_t)row * DIM_) : nullptr;
    float4 v[3];
    float s = 0.f, s2 = 0.f;
#pragma unroll
    for (int i = 0; i < 3; i++) {
        float4 a = y0r[i * 64 + lane];
        if (y1r) {
            float4 bb = y1r[i * 64 + lane];
            a.x += bb.x; a.y += bb.y; a.z += bb.z; a.w += bb.w;
        }
        v[i] = a;
        s += (a.x + a.y) + (a.z + a.w);
        s2 += (a.x * a.x + a.y * a.y) + (a.z * a.z + a.w * a.w);
    }
#pragma unroll
    for (int o = 1; o < 64; o <<= 1) { s += __shfl_xor(s, o); s2 += __shfl_xor(s2, o); }
    float mu = s * (1.f / 768.f);
    float var = s2 * (1.f / 768.f) - mu * mu;
    float rs = rsqrtf(var + 1e-5f);
    const float4* xr = (const float4*)(xin + (size_t)row * DIM_);
    const float4* g4 = (const float4*)g;
    const float4* b4 = (const float4*)be;
    float4* of = (float4*)(outf + (size_t)row * DIM_);
#pragma unroll
    for (int i = 0; i < 3; i++) {
        int c = i * 64 + lane;
        float4 gg = g4[c], bb = b4[c], xx = xr[c];
        float4 o;
        o.x = xx.x + (v[i].x - mu) * rs * gg.x + bb.x;
        o.y = xx.y + (v[i].y - mu) * rs * gg.y + bb.y;
        o.z = xx.z + (v[i].z - mu) * rs * gg.z + bb.z;
        o.w = xx.w + (v[i].w - mu) * rs * gg.w + bb.w;
        of[c] = o;
        if (outbf) {
            ushort4 ob;
            ob.x = f2bf(o.x); ob.y = f2bf(o.y); ob.z = f2bf(o.z); ob.w = f2bf(o.w);
            ((ushort4*)(outbf + (size_t)row * DIM_))[c] = ob;
        }
    }
}

// ---------------- launch ----------------
extern "C" void kernel_launch(void* const* d_in, const int* in_sizes, int n_in,
                              void* d_out, int out_size, void* d_ws, size_t ws_size,
                              hipStream_t stream)
{
    const float* x    = (const float*)d_in[0];
    const float* Wqkv = (const float*)d_in[1];
    const float* bqkv = (const float*)d_in[2];
    const float* Wproj= (const float*)d_in[3];
    const float* bproj= (const float*)d_in[4];
    const float* W1   = (const float*)d_in[5];
    const float* b1   = (const float*)d_in[6];
    const float* W2   = (const float*)d_in[7];
    const float* b2   = (const float*)d_in[8];
    const float* g1   = (const float*)d_in[9];
    const float* be1  = (const float*)d_in[10];
    const float* g2   = (const float*)d_in[11];
    const float* be2  = (const float*)d_in[12];
    float* out = (float*)d_out;

    char* ws = (char*)d_ws;
    size_t off = 0;
    auto alloc = [&](size_t bytes) -> void* {
        void* p = ws + off;
        off += (bytes + 255) & ~(size_t)255;
        return p;
    };
    // weights first (live all along)
    ushort* wqkvT  = (ushort*)alloc((size_t)2304 * 768 * 2);
    ushort* wprojT = (ushort*)alloc((size_t)768 * 768 * 2);
    ushort* w1T    = (ushort*)alloc((size_t)3072 * 768 * 2);
    ushort* w2T    = (ushort*)alloc((size_t)768 * 3072 * 2);
    // BLOCK_A: xbf/qb/kb/vT (dead after attn) — aliased by hbf afterwards.
    ushort* xbf    = (ushort*)alloc((size_t)ROWS_ * DIM_ * 2);
    ushort* qb     = (ushort*)alloc((size_t)ROWS_ * DIM_ * 2);
    ushort* kb     = (ushort*)alloc((size_t)ROWS_ * DIM_ * 2);
    ushort* vT     = (ushort*)alloc((size_t)ROWS_ * DIM_ * 2);
    ushort* hbf    = xbf;  // alias: 4*ROWS*DIM*2 == ROWS*HID*2
    ushort* aobf   = (ushort*)alloc((size_t)ROWS_ * DIM_ * 2);
    float*  projp  = (float*) alloc((size_t)2 * ROWS_ * DIM_ * 4); // split-K partials
    float*  x1f    = (float*) alloc((size_t)ROWS_ * DIM_ * 4);
    ushort* x1bf   = (ushort*)alloc((size_t)ROWS_ * DIM_ * 2);
    float*  projp1 = projp + (size_t)ROWS_ * DIM_;

    // prep
    cast_bf16_kernel<<<(ROWS_ * DIM_ / 4 + 255) / 256, 256, 0, stream>>>(x, xbf, ROWS_ * DIM_ / 4);
    transpose_cast_kernel<<<dim3(2304 / 32, 768 / 32), dim3(32, 8), 0, stream>>>(Wqkv, wqkvT, 768, 2304);
    transpose_cast_kernel<<<dim3(768 / 32, 768 / 32), dim3(32, 8), 0, stream>>>(Wproj, wprojT, 768, 768);
    transpose_cast_kernel<<<dim3(3072 / 32, 768 / 32), dim3(32, 8), 0, stream>>>(W1, w1T, 768, 3072);
    transpose_cast_kernel<<<dim3(768 / 32, 3072 / 32), dim3(32, 8), 0, stream>>>(W2, w2T, 3072, 768);

    // qkv = x @ Wqkv + bqkv -> scatter into q/k/vT  (1152 blocks, nx=18)
    gemm_bt<EPI_QKV><<<1152, 256, 0, stream>>>(
        xbf, wqkvT, bqkv, nullptr, nullptr, qb, kb, vT, ROWS_, 2304, 768, 18, 1, 768);

    // attention -> aobf (768 blocks, XCD-local heads)
    attn_kernel<<<768, 256, 0, stream>>>(qb, kb, vT, aobf);

    // proj: split-K x2 (768 blocks, nx=6, Ksl=384) -> projp0, projp1
    gemm_bt<EPI_F32><<<768, 256, 0, stream>>>(
        aobf, wprojT, bproj, projp, nullptr, nullptr, nullptr, nullptr, ROWS_, 768, 768, 6, 2, 384);

    // x1 = x + LN(projp0 + projp1)
    ln_residual_kernel<<<ROWS_ / 4, 256, 0, stream>>>(x, projp, projp1, g1, be1, x1f, x1bf, ROWS_);

    // h = gelu(x1 @ W1 + b1)  (1536 blocks, nx=24) — hbf aliases dead BLOCK_A
    gemm_bt<EPI_GELU><<<1536, 256, 0, stream>>>(
        x1bf, w1T, b1, nullptr, hbf, nullptr, nullptr, nullptr, ROWS_, 3072, 768, 24, 1, 768);

    // mlp = h @ W2 + b2: split-K x2 (768 blocks, nx=6, Ksl=1536) -> projp0, projp1
    gemm_bt<EPI_F32><<<768, 256, 0, stream>>>(
        hbf, w2T, b2, projp, nullptr, nullptr, nullptr, nullptr, ROWS_, 768, 3072, 6, 2, 1536);

    // out = x1 + LN(mlp0 + mlp1)
    ln_residual_kernel<<<ROWS_ / 4, 256, 0, stream>>>(x1f, projp, projp1, g2, be2, out, nullptr, ROWS_);
}